// Round 11
// baseline (243.253 us; speedup 1.0000x reference)
//
#include <hip/hip_runtime.h>

#define BATCH 65536
#define IN_DIM 128
#define INT_NODES 255
#define LEAF 256
#define OUT_DIM 8
#define AMB_TH 4e-3f   // fp16-GEMM z error ~3e-4 RMS; 13-sigma guard band

typedef float    f4v __attribute__((ext_vector_type(4)));
typedef _Float16 h8v __attribute__((ext_vector_type(8)));

// Fused prepass: blocks [0,64) = LDS-tiled transpose Wor -> Wor_t[l][o][i];
// blocks [64,192) = Wp -> fp16 MFMA B-fragments (node 255 zero-pad).
__global__ __launch_bounds__(256) void prep(const float* __restrict__ Wor,
                                            float* __restrict__ Wor_t,
                                            const float* __restrict__ Wp,
                                            _Float16* __restrict__ Bf) {
    if (blockIdx.x < 64) {
        __shared__ float t[64][65];
        const int rt = blockIdx.x >> 2, ct = blockIdx.x & 3;  // 16 x 4 tiles of 64x64
        const int r0 = rt * 64, c0 = ct * 64;
        const int tx = threadIdx.x & 63, ty = threadIdx.x >> 6;
#pragma unroll
        for (int p = 0; p < 16; ++p) {
            int r = ty + p * 4;
            t[r][tx] = Wor[(size_t)(r0 + r) * 256 + c0 + tx];     // coalesced
        }
        __syncthreads();
#pragma unroll
        for (int p = 0; p < 16; ++p) {
            int r = ty + p * 4;
            Wor_t[(size_t)(c0 + r) * 1024 + r0 + tx] = t[tx][r];  // coalesced
        }
    } else {
        // B-frag (16x16x32): B[k = ks*32+(lane>>4)*8+j][n = ntg*16+(lane&15)],
        // slot = ((ks*16+ntg)*64+lane)*8+j.
        int slot = (blockIdx.x - 64) * 256 + threadIdx.x;   // 32768
        int j    = slot & 7;
        int lane = (slot >> 3) & 63;
        int ntg  = (slot >> 9) & 15;
        int ks   = slot >> 13;
        int n = ntg * 16 + (lane & 15);
        int k = ks * 32 + (lane >> 4) * 8 + j;
        float v = (n < INT_NODES) ? Wp[n * IN_DIM + k] : 0.f;
        Bf[slot] = (_Float16)v;
    }
}

// Kernel A: fp16 MFMA GEMM + compress (unchanged from R10 -- not the top cost).
__global__ __launch_bounds__(256) void gemm_sign(
    const float* __restrict__ x, const float* __restrict__ bp,
    const _Float16* __restrict__ Bfg,
    unsigned char* __restrict__ sgnp, float* __restrict__ asum_p) {

    const int tid  = threadIdx.x;
    const int wave = tid >> 6;
    const int lane = tid & 63;
    const int c = lane & 15;
    const int g = lane >> 4;
    const int rowbase = blockIdx.x * 64;

    f4v acc[4][4];   // [mt][nt]
#pragma unroll
    for (int mt = 0; mt < 4; ++mt)
#pragma unroll
        for (int nt = 0; nt < 4; ++nt) acc[mt][nt] = (f4v){0.f, 0.f, 0.f, 0.f};

    const h8v* Bf8 = (const h8v*)Bfg;
    const float* xbase = x + (size_t)rowbase * IN_DIM;

#pragma unroll
    for (int ks = 0; ks < 4; ++ks) {
        h8v ah[4];
#pragma unroll
        for (int mt = 0; mt < 4; ++mt) {
            const float* p = xbase + (size_t)(mt * 16 + c) * IN_DIM + ks * 32 + g * 8;
            float4 v0 = *reinterpret_cast<const float4*>(p);
            float4 v1 = *reinterpret_cast<const float4*>(p + 4);
            h8v a;
            a[0] = (_Float16)v0.x; a[1] = (_Float16)v0.y;
            a[2] = (_Float16)v0.z; a[3] = (_Float16)v0.w;
            a[4] = (_Float16)v1.x; a[5] = (_Float16)v1.y;
            a[6] = (_Float16)v1.z; a[7] = (_Float16)v1.w;
            ah[mt] = a;
        }
#pragma unroll
        for (int nt = 0; nt < 4; ++nt) {
            h8v b = Bf8[(ks * 16 + (wave * 4 + nt)) * 64 + lane];  // coalesced, L2-hot
#pragma unroll
            for (int mt = 0; mt < 4; ++mt)
                acc[mt][nt] = __builtin_amdgcn_mfma_f32_16x16x32_f16(ah[mt], b, acc[mt][nt], 0, 0, 0);
        }
    }

    // compress: 2-bit codes packed 4 nodes (nt)/byte, 4 rows/u32.
    // C/D layout: col n = wave*64 + nt*16 + c, row m = mt*16 + g*4 + r.
    float pp[4][4];
    unsigned bytes[4][4];
#pragma unroll
    for (int mt = 0; mt < 4; ++mt)
#pragma unroll
        for (int r = 0; r < 4; ++r) { pp[mt][r] = 0.f; bytes[mt][r] = 0u; }

#pragma unroll
    for (int nt = 0; nt < 4; ++nt) {
        const int n = wave * 64 + nt * 16 + c;
        const float bpv = (n < INT_NODES) ? bp[n] : 0.f;   // 1KB, L1-hot
#pragma unroll
        for (int mt = 0; mt < 4; ++mt)
#pragma unroll
            for (int r = 0; r < 4; ++r) {
                float v = acc[mt][nt][r] + bpv;
                float av = fabsf(v);
                if (n < INT_NODES) pp[mt][r] += av;
                unsigned code = (v < 0.f ? 1u : 0u) | (av < AMB_TH ? 2u : 0u);
                bytes[mt][r] |= code << (2 * nt);
            }
    }
    // decode: node n -> plane = (n>>6)*16 + (n&15), shift = ((n>>4)&3)*2
#pragma unroll
    for (int mt = 0; mt < 4; ++mt) {
        unsigned w32 = bytes[mt][0] | (bytes[mt][1] << 8)
                     | (bytes[mt][2] << 16) | (bytes[mt][3] << 24);
        *reinterpret_cast<unsigned*>(
            &sgnp[(size_t)(wave * 16 + c) * BATCH + rowbase + mt * 16 + g * 4]) = w32;
    }
#pragma unroll
    for (int m = 1; m < 16; m <<= 1)
#pragma unroll
        for (int mt = 0; mt < 4; ++mt)
#pragma unroll
            for (int r = 0; r < 4; ++r) pp[mt][r] += __shfl_xor(pp[mt][r], m);
    asum_p[(size_t)wave * BATCH + rowbase + (c >> 2) * 16 + g * 4 + (c & 3)] = pp[c >> 2][c & 3];
}

// Kernel B: traversal + per-block leaf histogram. 1 thread/row.
__global__ __launch_bounds__(256) void traverse(
    const float* __restrict__ x, const float* __restrict__ Wp,
    const float* __restrict__ bp, const unsigned char* __restrict__ sgnp,
    const float* __restrict__ asum_p,
    int* __restrict__ leafb, float* __restrict__ psb,
    unsigned* __restrict__ partial) {

    __shared__ int cnt[256];
    cnt[threadIdx.x] = 0;
    __syncthreads();

    const int row = blockIdx.x * 256 + threadIdx.x;

    float s = asum_p[row] + asum_p[BATCH + row]
            + asum_p[2 * BATCH + row] + asum_p[3 * BATCH + row];
    const float fac = s * (1.0f / (float)INT_NODES);
    // p* of argmax leaf: sum_l exp(and_z_l - 8 fac) = (1 + e^{-2 fac})^8.
    const float e = expf(-2.0f * fac);
    const float q = 1.0f + e;
    const float q2 = q * q, q4 = q2 * q2, q8 = q4 * q4;

    int node = 0;
#pragma unroll
    for (int d = 0; d < 8; ++d) {
        unsigned b = sgnp[(size_t)((node >> 6) * 16 + (node & 15)) * BATCH + row];
        int code = (int)((b >> (((node >> 4) & 3) * 2)) & 3u);
        int neg;
        if (code & 2) {          // ~2.6% of rows: exact sign via fp64
            double zd = (double)bp[node];
            const float* wr = Wp + node * IN_DIM;
            const float* xrow = x + (size_t)row * IN_DIM;
            for (int k = 0; k < IN_DIM; ++k)
                zd = fma((double)wr[k], (double)xrow[k], zd);
            neg = (zd < 0.0) ? 1 : 0;
        } else {
            neg = code & 1;
        }
        node = 2 * node + 1 + neg;
    }
    const int leaf = node - INT_NODES;
    leafb[row] = leaf;
    psb[row] = 1.0f / q8;

    atomicAdd(&cnt[leaf], 1);
    __syncthreads();
    partial[blockIdx.x * 256 + threadIdx.x] = (unsigned)cnt[threadIdx.x];
}

// Kernel C: single-block scan -> per-(block,leaf) scatter bases.
__global__ __launch_bounds__(256) void scan(const unsigned* __restrict__ partial,
                                            unsigned* __restrict__ base) {
    __shared__ unsigned tot[256];
    const int leaf = threadIdx.x;
    unsigned t = 0;
    for (int b = 0; b < 256; ++b) t += partial[b * 256 + leaf];   // coalesced
    tot[leaf] = t;
    __syncthreads();
    for (int off = 1; off < 256; off <<= 1) {       // Hillis-Steele inclusive
        unsigned v = (leaf >= off) ? tot[leaf - off] : 0u;
        __syncthreads();
        tot[leaf] += v;
        __syncthreads();
    }
    unsigned running = (leaf == 0) ? 0u : tot[leaf - 1];   // exclusive
    for (int b = 0; b < 256; ++b) {
        base[b * 256 + leaf] = running;                     // coalesced
        running += partial[b * 256 + leaf];
    }
}

// Kernel D: scatter rows into leaf-sorted order (LDS-atomic rank, no global
// atomic contention).
__global__ __launch_bounds__(256) void scatter(const int* __restrict__ leafb,
                                               const unsigned* __restrict__ base,
                                               int* __restrict__ rowidx) {
    __shared__ int cnt[256];
    cnt[threadIdx.x] = 0;
    __syncthreads();
    const int row = blockIdx.x * 256 + threadIdx.x;
    const int leaf = leafb[row];
    int rank = atomicAdd(&cnt[leaf], 1);
    rowidx[base[blockIdx.x * 256 + leaf] + rank] = row;
}

// Kernel E: heads over leaf-sorted positions. Neighboring threads now share a
// leaf -> Wor_t/bor loads are broadcast (was: 64 distinct lines per load).
__global__ __launch_bounds__(256) void heads(
    const float* __restrict__ x, const int* __restrict__ rowidx,
    const int* __restrict__ leafb, const float* __restrict__ psb,
    const float* __restrict__ Wor_t, const float* __restrict__ bor,
    const float* __restrict__ stds,
    float* __restrict__ out, float* __restrict__ stdo) {

    const int gtid = blockIdx.x * 256 + threadIdx.x;
    const int pos = gtid >> 3;
    const int o = gtid & 7;

    const int row = rowidx[pos];
    const int leaf = leafb[row];
    const float ps = psb[row];
    const float* xrow = x + (size_t)row * IN_DIM;
    const float* wo = Wor_t + (size_t)leaf * 1024 + o * IN_DIM;   // wave-near-uniform
    const float* bo = bor + o * IN_DIM;                           // uniform over rows

    float s0 = 0.f, s1 = 0.f, s2 = 0.f, s3 = 0.f;
    float t0 = 0.f, t1 = 0.f, t2 = 0.f, t3 = 0.f;
#pragma unroll
    for (int ch = 0; ch < IN_DIM; ch += 8) {
        float4 x0 = *reinterpret_cast<const float4*>(xrow + ch);
        float4 x1 = *reinterpret_cast<const float4*>(xrow + ch + 4);
        float4 w0 = *reinterpret_cast<const float4*>(wo + ch);
        float4 w1 = *reinterpret_cast<const float4*>(wo + ch + 4);
        float4 c0 = *reinterpret_cast<const float4*>(bo + ch);
        float4 c1 = *reinterpret_cast<const float4*>(bo + ch + 4);
        s0 = fmaf(w0.x, x0.x, s0); s1 = fmaf(w0.y, x0.y, s1);
        s2 = fmaf(w0.z, x0.z, s2); s3 = fmaf(w0.w, x0.w, s3);
        s0 = fmaf(w1.x, x1.x, s0); s1 = fmaf(w1.y, x1.y, s1);
        s2 = fmaf(w1.z, x1.z, s2); s3 = fmaf(w1.w, x1.w, s3);
        t0 = fmaf(c0.x, x0.x, t0); t1 = fmaf(c0.y, x0.y, t1);
        t2 = fmaf(c0.z, x0.z, t2); t3 = fmaf(c0.w, x0.w, t3);
        t0 = fmaf(c1.x, x1.x, t0); t1 = fmaf(c1.y, x1.y, t1);
        t2 = fmaf(c1.z, x1.z, t2); t3 = fmaf(c1.w, x1.w, t3);
    }
    out[(size_t)row * OUT_DIM + o] = ps * ((s0 + s1) + (s2 + s3))
                                   + ((t0 + t1) + (t2 + t3));
    float sd = ps * stds[leaf * OUT_DIM + o];
    stdo[(size_t)row * OUT_DIM + o] = fminf(fmaxf(sd, -20.0f), 2.0f);
}

extern "C" void kernel_launch(void* const* d_in, const int* in_sizes, int n_in,
                              void* d_out, int out_size, void* d_ws, size_t ws_size,
                              hipStream_t stream) {
    const float* x    = (const float*)d_in[0];
    const float* Wp   = (const float*)d_in[1];
    const float* bp   = (const float*)d_in[2];
    // d_in[3] = Wand -- folded into the traversal, unused.
    const float* Wor  = (const float*)d_in[4];
    const float* bor  = (const float*)d_in[5];
    const float* stds = (const float*)d_in[6];
    float* out = (float*)d_out;

    char* ws = (char*)d_ws;
    float* wor_t        = (float*)(ws);                           // 1 MB
    _Float16* Bf        = (_Float16*)(ws + (1 << 20));            // 64 KB
    unsigned char* sgnp = (unsigned char*)(ws + (2 << 20));       // 4 MB
    float* asum_p       = (float*)(ws + (6 << 20));               // 1 MB
    int* leafb          = (int*)(ws + (7 << 20));                 // 256 KB
    float* psb          = (float*)(ws + (7 << 20) + (256 << 10)); // 256 KB
    unsigned* partial   = (unsigned*)(ws + (7 << 20) + (512 << 10)); // 256 KB
    unsigned* basep     = (unsigned*)(ws + (7 << 20) + (768 << 10)); // 256 KB
    int* rowidx         = (int*)(ws + (8 << 20));                 // 256 KB
    // total ws use: 8.25 MB

    prep<<<192, 256, 0, stream>>>(Wor, wor_t, Wp, Bf);
    gemm_sign<<<BATCH / 64, 256, 0, stream>>>(x, bp, Bf, sgnp, asum_p);
    traverse<<<BATCH / 256, 256, 0, stream>>>(x, Wp, bp, sgnp, asum_p,
                                              leafb, psb, partial);
    scan<<<1, 256, 0, stream>>>(partial, basep);
    scatter<<<BATCH / 256, 256, 0, stream>>>(leafb, basep, rowidx);
    heads<<<(BATCH * 8) / 256, 256, 0, stream>>>(x, rowidx, leafb, psb,
                                                 wor_t, bor, stds,
                                                 out, out + (size_t)BATCH * OUT_DIM);
}

// Round 12
// 132.319 us; speedup vs baseline: 1.8384x; 1.8384x over previous
//
#include <hip/hip_runtime.h>

#define BATCH 65536
#define IN_DIM 128
#define INT_NODES 255
#define LEAF 256
#define OUT_DIM 8
#define AMB_TH 4e-3f   // fp16-GEMM z error ~3e-4 RMS; wide guard band

typedef float    f4v __attribute__((ext_vector_type(4)));
typedef _Float16 h8v __attribute__((ext_vector_type(8)));

// Prepass: blocks [0,64) = LDS-tiled transpose Wor -> Wor_t[l][o][i];
// blocks [64,192) = Wp -> fp16 MFMA B-fragments (node 255 zero-pad).
__global__ __launch_bounds__(256) void prep(const float* __restrict__ Wor,
                                            float* __restrict__ Wor_t,
                                            const float* __restrict__ Wp,
                                            _Float16* __restrict__ Bf) {
    if (blockIdx.x < 64) {
        __shared__ float t[64][65];
        const int rt = blockIdx.x >> 2, ct = blockIdx.x & 3;  // 16 x 4 tiles of 64x64
        const int r0 = rt * 64, c0 = ct * 64;
        const int tx = threadIdx.x & 63, ty = threadIdx.x >> 6;
#pragma unroll
        for (int p = 0; p < 16; ++p) {
            int r = ty + p * 4;
            t[r][tx] = Wor[(size_t)(r0 + r) * 256 + c0 + tx];     // coalesced
        }
        __syncthreads();
#pragma unroll
        for (int p = 0; p < 16; ++p) {
            int r = ty + p * 4;
            Wor_t[(size_t)(c0 + r) * 1024 + r0 + tx] = t[tx][r];  // coalesced
        }
    } else {
        // B-frag (16x16x32): B[k = ks*32+(lane>>4)*8+j][n = ntg*16+(lane&15)],
        // slot = ((ks*16+ntg)*64+lane)*8+j.
        int slot = (blockIdx.x - 64) * 256 + threadIdx.x;   // 32768
        int j    = slot & 7;
        int lane = (slot >> 3) & 63;
        int ntg  = (slot >> 9) & 15;
        int ks   = slot >> 13;
        int n = ntg * 16 + (lane & 15);
        int k = ks * 32 + (lane >> 4) * 8 + j;
        float v = (n < INT_NODES) ? Wp[n * IN_DIM + k] : 0.f;
        Bf[slot] = (_Float16)v;
    }
}

// Single fused main kernel. Block = 256 threads = 64 rows. 3 barriers, no
// __shfl (R11: compiler shfl lowering allocated 16KB LDS + 7.3M bank
// conflicts), no wave0-only phase, heads loads K-interleaved so 4 lanes share
// each 64B line of the leaf-scattered Wor_t gather.
__global__ __launch_bounds__(256) void dgt_main(
    const float* __restrict__ x, const float* __restrict__ Wp,
    const float* __restrict__ bp, const _Float16* __restrict__ Bfg,
    const float* __restrict__ Wor_t, const float* __restrict__ bor,
    const float* __restrict__ stds,
    float* __restrict__ out, float* __restrict__ stdo) {

    __shared__ unsigned char sgn[LEAF * 16];  // 4KB: code(n,r) -> sgn[n*16+(r>>2)], shift (r&3)*2
    __shared__ float P[64 * 68];              // 17.4KB: |z| partials [(w*16+c)*68 + r]
    __shared__ float S[256];                  // 1KB: [q*64 + r] quarter-sums
    __shared__ float H[64 * 33];              // 8.4KB: heads partials [r*33 + o*4 + kq]
    __shared__ float psL[64];
    __shared__ int   leafL[64];

    const int tid  = threadIdx.x;
    const int wave = tid >> 6;
    const int lane = tid & 63;
    const int c = lane & 15;
    const int g = lane >> 4;
    const int rowbase = blockIdx.x * 64;

    // ---- phase 1: fp16 MFMA quadrant (wave w: cols [64w,64w+64), rows 0..63) ----
    f4v acc[4][4];
#pragma unroll
    for (int mt = 0; mt < 4; ++mt)
#pragma unroll
        for (int nt = 0; nt < 4; ++nt) acc[mt][nt] = (f4v){0.f, 0.f, 0.f, 0.f};

    const h8v* Bf8 = (const h8v*)Bfg;
    const float* xbase = x + (size_t)rowbase * IN_DIM;
#pragma unroll
    for (int ks = 0; ks < 4; ++ks) {
        h8v ah[4];
#pragma unroll
        for (int mt = 0; mt < 4; ++mt) {
            const float* p = xbase + (size_t)(mt * 16 + c) * IN_DIM + ks * 32 + g * 8;
            float4 v0 = *reinterpret_cast<const float4*>(p);
            float4 v1 = *reinterpret_cast<const float4*>(p + 4);
            h8v a;
            a[0] = (_Float16)v0.x; a[1] = (_Float16)v0.y;
            a[2] = (_Float16)v0.z; a[3] = (_Float16)v0.w;
            a[4] = (_Float16)v1.x; a[5] = (_Float16)v1.y;
            a[6] = (_Float16)v1.z; a[7] = (_Float16)v1.w;
            ah[mt] = a;
        }
#pragma unroll
        for (int nt = 0; nt < 4; ++nt) {
            h8v b = Bf8[(ks * 16 + (wave * 4 + nt)) * 64 + lane];  // coalesced, L2-hot
#pragma unroll
            for (int mt = 0; mt < 4; ++mt)
                acc[mt][nt] = __builtin_amdgcn_mfma_f32_16x16x32_f16(ah[mt], b, acc[mt][nt], 0, 0, 0);
        }
    }

    // ---- phase 2: compress to sgn LDS + |z+bp| partials to P LDS ----
    // C/D: col n = wave*64 + nt*16 + c, row m = mt*16 + g*4 + rr.
    {
        float pp[4][4];
#pragma unroll
        for (int mt = 0; mt < 4; ++mt)
#pragma unroll
            for (int rr = 0; rr < 4; ++rr) pp[mt][rr] = 0.f;
#pragma unroll
        for (int nt = 0; nt < 4; ++nt) {
            const int n = wave * 64 + nt * 16 + c;
            const float bpv = (n < INT_NODES) ? bp[n] : 0.f;   // 1KB, L1-hot
#pragma unroll
            for (int mt = 0; mt < 4; ++mt) {
                unsigned by = 0;
#pragma unroll
                for (int rr = 0; rr < 4; ++rr) {
                    float v = acc[mt][nt][rr] + bpv;
                    float av = fabsf(v);
                    if (n < INT_NODES) pp[mt][rr] += av;
                    by |= ((v < 0.f ? 1u : 0u) | (av < AMB_TH ? 2u : 0u)) << (2 * rr);
                }
                sgn[n * 16 + mt * 4 + g] = (unsigned char)by;
            }
        }
#pragma unroll
        for (int mt = 0; mt < 4; ++mt)
#pragma unroll
            for (int rr = 0; rr < 4; ++rr)
                P[(wave * 16 + c) * 68 + mt * 16 + g * 4 + rr] = pp[mt][rr];
    }
    __syncthreads();   // #1

    // ---- phase 3: quarter-reduce P over c: thread (r = tid&63, q = tid>>6) ----
    {
        const int r = tid & 63, q = tid >> 6;
        float s = 0.f;
#pragma unroll
        for (int cc = 0; cc < 16; ++cc) s += P[(q * 16 + cc) * 68 + r];
        S[q * 64 + r] = s;
    }
    __syncthreads();   // #2

    // ---- phase 4: traversal (x4 redundant over kq) + heads partials.
    //      thread = (row r = tid>>2, K-quarter kq = tid&3). ----
    {
        const int r = tid >> 2, kq = tid & 3;
        float asum = S[r] + S[64 + r] + S[128 + r] + S[192 + r];
        const float fac = asum * (1.0f / (float)INT_NODES);
        // p* of argmax leaf: sum_l exp(and_z_l - 8 fac) = (1 + e^{-2 fac})^8.
        const float e = expf(-2.0f * fac);
        const float qq = 1.0f + e;
        const float q2 = qq * qq, q4 = q2 * q2, q8 = q4 * q4;
        const float ps = 1.0f / q8;

        int node = 0;
#pragma unroll
        for (int d = 0; d < 8; ++d) {
            unsigned by = sgn[node * 16 + (r >> 2)];
            int code = (int)((by >> ((r & 3) * 2)) & 3u);
            int neg;
            if (code & 2) {          // rare: exact sign via fp64 from global
                double zd = (double)bp[node];
                const float* wr = Wp + node * IN_DIM;
                const float* xrow = x + (size_t)(rowbase + r) * IN_DIM;
                for (int k = 0; k < IN_DIM; ++k)
                    zd = fma((double)wr[k], (double)xrow[k], zd);
                neg = (zd < 0.0) ? 1 : 0;
            } else {
                neg = code & 1;
            }
            node = 2 * node + 1 + neg;
        }
        const int leaf = node - INT_NODES;
        if (kq == 0) { psL[r] = ps; leafL[r] = leaf; }

        // heads partials, K-interleaved: thread kq takes float4 chunks at
        // offset (step*4+kq)*4 -- the 4 kq lanes cover one 64B line together.
        const float* xr = x + (size_t)(rowbase + r) * IN_DIM;    // L1-hot
        const float* wl = Wor_t + (size_t)leaf * 1024;
        float hp[8];
#pragma unroll
        for (int o = 0; o < 8; ++o) hp[o] = 0.f;
        float tp[8];
#pragma unroll
        for (int o = 0; o < 8; ++o) tp[o] = 0.f;
#pragma unroll
        for (int step = 0; step < 8; ++step) {
            const int off = (step * 4 + kq) * 4;
            float4 xv = *reinterpret_cast<const float4*>(xr + off);
#pragma unroll
            for (int o = 0; o < 8; ++o) {
                float4 wv = *reinterpret_cast<const float4*>(wl + o * IN_DIM + off);
                float4 bv = *reinterpret_cast<const float4*>(bor + o * IN_DIM + off);
                hp[o] = fmaf(wv.x, xv.x, hp[o]); hp[o] = fmaf(wv.y, xv.y, hp[o]);
                hp[o] = fmaf(wv.z, xv.z, hp[o]); hp[o] = fmaf(wv.w, xv.w, hp[o]);
                tp[o] = fmaf(bv.x, xv.x, tp[o]); tp[o] = fmaf(bv.y, xv.y, tp[o]);
                tp[o] = fmaf(bv.z, xv.z, tp[o]); tp[o] = fmaf(bv.w, xv.w, tp[o]);
            }
        }
#pragma unroll
        for (int o = 0; o < 8; ++o)
            H[r * 33 + o * 4 + kq] = ps * hp[o] + tp[o];
    }
    __syncthreads();   // #3

    // ---- phase 5: final reduce + stores: thread (r = tid&63, pair p = tid>>6) ----
    {
        const int r = tid & 63, p = tid >> 6;
        const float ps = psL[r];
        const int leaf = leafL[r];
#pragma unroll
        for (int u = 0; u < 2; ++u) {
            const int o = p * 2 + u;
            float v = H[r * 33 + o * 4 + 0] + H[r * 33 + o * 4 + 1]
                    + H[r * 33 + o * 4 + 2] + H[r * 33 + o * 4 + 3];
            out[(size_t)(rowbase + r) * OUT_DIM + o] = v;
            float sd = ps * stds[leaf * OUT_DIM + o];
            stdo[(size_t)(rowbase + r) * OUT_DIM + o] = fminf(fmaxf(sd, -20.0f), 2.0f);
        }
    }
}

extern "C" void kernel_launch(void* const* d_in, const int* in_sizes, int n_in,
                              void* d_out, int out_size, void* d_ws, size_t ws_size,
                              hipStream_t stream) {
    const float* x    = (const float*)d_in[0];
    const float* Wp   = (const float*)d_in[1];
    const float* bp   = (const float*)d_in[2];
    // d_in[3] = Wand -- folded into the traversal, unused.
    const float* Wor  = (const float*)d_in[4];
    const float* bor  = (const float*)d_in[5];
    const float* stds = (const float*)d_in[6];
    float* out = (float*)d_out;

    char* ws = (char*)d_ws;
    float* wor_t = (float*)(ws);                  // 1 MB
    _Float16* Bf = (_Float16*)(ws + (1 << 20));   // 64 KB

    prep<<<192, 256, 0, stream>>>(Wor, wor_t, Wp, Bf);
    dgt_main<<<BATCH / 64, 256, 0, stream>>>(x, Wp, bp, Bf, wor_t, bor, stds,
                                             out, out + (size_t)BATCH * OUT_DIM);
}